// Round 2
// baseline (597.537 us; speedup 1.0000x reference)
//
#include <hip/hip_runtime.h>
#include <hip/hip_bf16.h>

// Problem constants
#define NSEQ 2048
#define NB   4
#define DIM  2048
#define HN   1024          // heads = DIM/2
#define FC   6144          // 3*DIM feat cols
#define MROWS 8192         // NSEQ*NB
#define CHUNKS 64
#define CLEN 32            // NSEQ/CHUNKS
#define NCH  4096          // NB*HN channels

typedef __bf16 bf16x8_t __attribute__((ext_vector_type(8)));
typedef float  f32x4_t  __attribute__((ext_vector_type(4)));

__device__ __forceinline__ float sigm(float x){ return 1.f/(1.f + __expf(-x)); }
__device__ __forceinline__ float bflo(unsigned p){ return __uint_as_float(p << 16); }
__device__ __forceinline__ float bfhi(unsigned p){ return __uint_as_float(p & 0xffff0000u); }
__device__ __forceinline__ unsigned short f2bf(float f){
  union { __hip_bfloat16 h; unsigned short u; } cv;
  cv.h = __float2bfloat16(f);
  return cv.u;
}

// ---------------------------------------------------------------- convert f32 -> bf16
__global__ __launch_bounds__(256) void cvt_bf16_4(const float4* __restrict__ in,
                                                  ushort4* __restrict__ out, int n4){
  int i = blockIdx.x * blockDim.x + threadIdx.x;
  int st = gridDim.x * blockDim.x;
  for (; i < n4; i += st){
    float4 v = in[i];
    ushort4 r;
    r.x = f2bf(v.x); r.y = f2bf(v.y); r.z = f2bf(v.z); r.w = f2bf(v.w);
    out[i] = r;
  }
}

// ---------------------------------------------------------------- bf16 NT GEMM + bias
// C[m,n] = sum_k A[m,k]*B[n,k] + bias[n].  A: MxK row-major bf16, B: NxK row-major bf16.
// 128x128 tile, BK=32, 4 waves (2x2), each wave 64x64 via 4x4 frags of 16x16x32 MFMA.
// OutT = float (final output) or __hip_bfloat16 (intermediate).
__device__ __forceinline__ void gl_lds16(const void* g, void* l){
  __builtin_amdgcn_global_load_lds((const __attribute__((address_space(1))) void*)g,
                                   (__attribute__((address_space(3))) void*)l, 16, 0, 0);
}

template <typename OutT>
__global__ __launch_bounds__(256) void gemm_bt(const __hip_bfloat16* __restrict__ A,
                                               const __hip_bfloat16* __restrict__ B,
                                               const float* __restrict__ bias,
                                               OutT* __restrict__ C,
                                               int M, int N, int K){
  __shared__ __align__(16) __hip_bfloat16 As[128*32];
  __shared__ __align__(16) __hip_bfloat16 Bs[128*32];
  const int tid  = threadIdx.x;
  const int wave = tid >> 6, lane = tid & 63;
  const int m0 = blockIdx.y * 128, n0 = blockIdx.x * 128;
  const int wr = wave >> 1, wc = wave & 1;          // wave -> 64x64 quadrant
  const int r  = lane & 15, q = lane >> 4;          // fragment row / k-group
  const int crow = lane >> 2;                       // staging: row within 16-row chunk
  const int ccol = (lane & 3) * 8;                  // staging: k offset (8 bf16 = 16B)

  f32x4_t acc[4][4] = {};

  for (int kt = 0; kt < K; kt += 32){
    // stage A/B tiles: 8 chunks of 512 elems each; wave w covers chunks {w, w+4}
    #pragma unroll
    for (int i = 0; i < 2; ++i){
      int c = wave + i*4;
      const __hip_bfloat16* gA = A + (size_t)(m0 + c*16 + crow)*K + kt + ccol;
      const __hip_bfloat16* gB = B + (size_t)(n0 + c*16 + crow)*K + kt + ccol;
      gl_lds16(gA, As + c*512);
      gl_lds16(gB, Bs + c*512);
    }
    __syncthreads();   // compiler emits vmcnt(0) drain before barrier -> staging visible

    bf16x8_t af[4], bfr[4];
    #pragma unroll
    for (int fm = 0; fm < 4; ++fm)
      af[fm] = *reinterpret_cast<const bf16x8_t*>(As + (wr*64 + fm*16 + r)*32 + q*8);
    #pragma unroll
    for (int fn = 0; fn < 4; ++fn)
      bfr[fn] = *reinterpret_cast<const bf16x8_t*>(Bs + (wc*64 + fn*16 + r)*32 + q*8);
    #pragma unroll
    for (int fm = 0; fm < 4; ++fm)
      #pragma unroll
      for (int fn = 0; fn < 4; ++fn)
        acc[fm][fn] = __builtin_amdgcn_mfma_f32_16x16x32_bf16(af[fm], bfr[fn], acc[fm][fn], 0, 0, 0);
    __syncthreads();   // all reads done before next stage overwrites
  }

  // epilogue: C/D layout col = lane&15, row = (lane>>4)*4 + j  (m89-verified)
  #pragma unroll
  for (int fn = 0; fn < 4; ++fn){
    int col = n0 + wc*64 + fn*16 + r;
    float bv = bias[col];
    #pragma unroll
    for (int fm = 0; fm < 4; ++fm){
      int row0 = m0 + wr*64 + fm*16 + q*4;
      #pragma unroll
      for (int j = 0; j < 4; ++j){
        float v = acc[fm][fn][j] + bv;
        if constexpr (__is_same(OutT, float))
          C[(size_t)(row0 + j)*N + col] = v;
        else
          C[(size_t)(row0 + j)*N + col] = __float2bfloat16(v);
      }
    }
  }
}

// ---------------------------------------------------------------- scan helpers
// feat viewed as uint pairs: row(n,b) = n*NB+b; uint offset = (n*NB+b)*3072 + h
//   + 0    -> inp pair (cols 2h, 2h+1)
//   + 1024 -> og  pair
//   + 2048 -> fg  pair
struct SV { float l0, l1, u00, u01, u10, u11; };
__device__ __forceinline__ SV stepv(const unsigned* __restrict__ fp, int rowu){
  unsigned pi = fp[rowu];
  unsigned pf = fp[rowu + 2048];
  SV s;
  s.l0 = sigm(bflo(pf)); s.l1 = sigm(bfhi(pf));
  float i0 = bflo(pi), i1 = bfhi(pi);
  i0 *= sigm(i0); i1 *= sigm(i1);            // silu
  float a0 = 1.f - s.l0, a1 = 1.f - s.l1;
  s.u00 = a0*i0; s.u01 = a0*i1; s.u10 = a1*i0; s.u11 = a1*i1;
  return s;
}

// S1: per-(channel, chunk) aggregates. P = prod lam (direction independent),
// hF = fwd local end-state, hR = rev local start-state. state layout [d][e].
__global__ __launch_bounds__(256) void scan_agg(const unsigned* __restrict__ feat,
    float* __restrict__ aggP, float4* __restrict__ aggHF, float4* __restrict__ aggHR){
  int ch = blockIdx.x*256 + threadIdx.x;   // 0..4095  (b*HN + h)
  int c  = blockIdx.y;
  int b = ch >> 10, h = ch & 1023;
  int base = b*3072 + h;
  int n0 = c*CLEN;
  float P0 = 1.f, P1 = 1.f;
  float f00=0,f01=0,f10=0,f11=0;
  for (int t = 0; t < CLEN; ++t){
    SV s = stepv(feat, (n0+t)*12288 + base);
    f00 = s.l0*f00 + s.u00; f01 = s.l0*f01 + s.u01;
    f10 = s.l1*f10 + s.u10; f11 = s.l1*f11 + s.u11;
    P0 *= s.l0; P1 *= s.l1;
  }
  float r00=0,r01=0,r10=0,r11=0;
  for (int t = CLEN-1; t >= 0; --t){
    SV s = stepv(feat, (n0+t)*12288 + base);
    r00 = s.l0*r00 + s.u00; r01 = s.l0*r01 + s.u01;
    r10 = s.l1*r10 + s.u10; r11 = s.l1*r11 + s.u11;
  }
  aggP[c*8192 + ch*2]     = P0;
  aggP[c*8192 + ch*2 + 1] = P1;
  aggHF[c*4096 + ch] = make_float4(f00,f01,f10,f11);
  aggHR[c*4096 + ch] = make_float4(r00,r01,r10,r11);
}

// S2: serial scan over chunk aggregates -> per-chunk carry-in states.
// thread per (ch,d,e): t = ch*4 + d*2 + e
__global__ __launch_bounds__(256) void scan_carry(const float* __restrict__ aggP,
    const float* __restrict__ aggHF, const float* __restrict__ aggHR,
    float* __restrict__ cF, float* __restrict__ cR){
  int t  = blockIdx.x*256 + threadIdx.x;   // 0..16383
  int pd = t >> 1;                         // ch*2 + d
  float s = 0.f;
  for (int c = 0; c < CHUNKS; ++c){
    cF[c*16384 + t] = s;
    s = aggP[c*8192 + pd]*s + aggHF[c*16384 + t];
  }
  s = 0.f;
  for (int c = CHUNKS-1; c >= 0; --c){
    cR[c*16384 + t] = s;
    s = aggP[c*8192 + pd]*s + aggHR[c*16384 + t];
  }
}

// S3a: forward pass, write o = sum_d og_d * fwd[d][e]   (fp32, (row, 2048))
__global__ __launch_bounds__(256) void scan_fwd(const unsigned* __restrict__ feat,
    const float4* __restrict__ cF, float2* __restrict__ o){
  int ch = blockIdx.x*256 + threadIdx.x;
  int c  = blockIdx.y;
  int b = ch >> 10, h = ch & 1023;
  int base = b*3072 + h;
  float4 hv = cF[c*4096 + ch];
  float h00=hv.x, h01=hv.y, h10=hv.z, h11=hv.w;
  for (int t = 0; t < CLEN; ++t){
    int n = c*CLEN + t;
    int rowu = n*12288 + base;
    SV s = stepv(feat, rowu);
    h00 = s.l0*h00 + s.u00; h01 = s.l0*h01 + s.u01;
    h10 = s.l1*h10 + s.u10; h11 = s.l1*h11 + s.u11;
    unsigned po = feat[rowu + 1024];
    float g0 = sigm(bflo(po)), g1 = sigm(bfhi(po));
    o[(n*NB + b)*1024 + h] = make_float2(g0*h00 + g1*h10, g0*h01 + g1*h11);
  }
}

// S3b: reverse pass, o += sum_d og_d * rev[d][e]
__global__ __launch_bounds__(256) void scan_rev(const unsigned* __restrict__ feat,
    const float4* __restrict__ cR, float2* __restrict__ o){
  int ch = blockIdx.x*256 + threadIdx.x;
  int c  = blockIdx.y;
  int b = ch >> 10, h = ch & 1023;
  int base = b*3072 + h;
  float4 hv = cR[c*4096 + ch];
  float h00=hv.x, h01=hv.y, h10=hv.z, h11=hv.w;
  for (int t = CLEN-1; t >= 0; --t){
    int n = c*CLEN + t;
    int rowu = n*12288 + base;
    SV s = stepv(feat, rowu);
    h00 = s.l0*h00 + s.u00; h01 = s.l0*h01 + s.u01;
    h10 = s.l1*h10 + s.u10; h11 = s.l1*h11 + s.u11;
    unsigned po = feat[rowu + 1024];
    float g0 = sigm(bflo(po)), g1 = sigm(bfhi(po));
    int idx = (n*NB + b)*1024 + h;
    float2 pv = o[idx];
    o[idx] = make_float2(pv.x + g0*h00 + g1*h10, pv.y + g0*h01 + g1*h11);
  }
}

// ---------------------------------------------------------------- LayerNorm over D, bf16 out
__global__ __launch_bounds__(256) void layernorm_k(const float* __restrict__ o,
    const float* __restrict__ gamma, const float* __restrict__ beta,
    __hip_bfloat16* __restrict__ out){
  int row = blockIdx.x, t = threadIdx.x;
  const float4* x = (const float4*)(o + (size_t)row*DIM);
  float4 a = x[t], b = x[t + 256];
  float s  = (a.x + a.y) + (a.z + a.w) + (b.x + b.y) + (b.z + b.w);
  float ss = (a.x*a.x + a.y*a.y) + (a.z*a.z + a.w*a.w)
           + (b.x*b.x + b.y*b.y) + (b.z*b.z + b.w*b.w);
  #pragma unroll
  for (int off = 32; off > 0; off >>= 1){
    s  += __shfl_down(s, off);
    ss += __shfl_down(ss, off);
  }
  __shared__ float red[8];
  int wv = t >> 6, ln = t & 63;
  if (ln == 0){ red[wv] = s; red[4 + wv] = ss; }
  __syncthreads();
  float S  = (red[0] + red[1]) + (red[2] + red[3]);
  float SS = (red[4] + red[5]) + (red[6] + red[7]);
  float mu = S * (1.f/DIM);
  float rs = rsqrtf(SS * (1.f/DIM) - mu*mu + 1e-5f);
  const float4* gp = (const float4*)gamma;
  const float4* bp = (const float4*)beta;
  float4 g0 = gp[t], g1 = gp[t + 256], be0 = bp[t], be1 = bp[t + 256];
  ushort4* op = (ushort4*)(out + (size_t)row*DIM);
  ushort4 r0, r1;
  r0.x = f2bf((a.x - mu)*rs*g0.x + be0.x);
  r0.y = f2bf((a.y - mu)*rs*g0.y + be0.y);
  r0.z = f2bf((a.z - mu)*rs*g0.z + be0.z);
  r0.w = f2bf((a.w - mu)*rs*g0.w + be0.w);
  r1.x = f2bf((b.x - mu)*rs*g1.x + be1.x);
  r1.y = f2bf((b.y - mu)*rs*g1.y + be1.y);
  r1.z = f2bf((b.z - mu)*rs*g1.z + be1.z);
  r1.w = f2bf((b.w - mu)*rs*g1.w + be1.w);
  op[t] = r0; op[t + 256] = r1;
}

// ---------------------------------------------------------------- launch
extern "C" void kernel_launch(void* const* d_in, const int* in_sizes, int n_in,
                              void* d_out, int out_size, void* d_ws, size_t ws_size,
                              hipStream_t stream){
  (void)in_sizes; (void)n_in; (void)out_size;
  const float* x     = (const float*)d_in[0];   // (N,B,D)
  const float* W_in  = (const float*)d_in[1];   // (3D,D)
  const float* b_in  = (const float*)d_in[2];   // (3D)
  const float* gamma = (const float*)d_in[3];   // (D)
  const float* beta  = (const float*)d_in[4];   // (D)
  const float* W_out = (const float*)d_in[5];   // (D,D)
  const float* b_out = (const float*)d_in[6];   // (D)
  float* out = (float*)d_out;                   // (N,B,D) fp32 (reference output dtype)

  // ---- workspace layout with aliasing (total 186 MiB) ----
  // [feat 96MiB][U 64MiB][Wob 8MiB][agg 18MiB]
  //   U: phase1 = xb(32MiB)+Wib(24MiB)  (dead after GEMM1)
  //      phase2 = o fp32 (64MiB)
  //   oln(32MiB) aliases feat (dead after scan_rev)
  char* p = (char*)d_ws;
  auto carve = [&](size_t bytes) -> char* {
    char* r = p; p += (bytes + 255) & ~(size_t)255; return r;
  };
  __hip_bfloat16* feat = (__hip_bfloat16*)carve((size_t)MROWS*FC*2);      // 96 MiB
  char* U              = carve((size_t)MROWS*DIM*4);                      // 64 MiB
  __hip_bfloat16* Wob  = (__hip_bfloat16*)carve((size_t)DIM*DIM*2);       //  8 MiB
  float* aggP  = (float*)carve((size_t)CHUNKS*8192*4);                    //  2 MiB
  float* aggHF = (float*)carve((size_t)CHUNKS*16384*4);                   //  4 MiB
  float* aggHR = (float*)carve((size_t)CHUNKS*16384*4);                   //  4 MiB
  float* cF    = (float*)carve((size_t)CHUNKS*16384*4);                   //  4 MiB
  float* cR    = (float*)carve((size_t)CHUNKS*16384*4);                   //  4 MiB
  if ((size_t)(p - (char*)d_ws) > ws_size) return;  // insufficient scratch

  __hip_bfloat16* xb  = (__hip_bfloat16*)U;                               // 32 MiB (phase 1)
  __hip_bfloat16* Wib = (__hip_bfloat16*)(U + (size_t)MROWS*DIM*2);       // 24 MiB (phase 1)
  float* o            = (float*)U;                                        // 64 MiB (phase 2+)
  __hip_bfloat16* oln = (__hip_bfloat16*)feat;                            // 32 MiB (phase 3)

  // 1) convert inputs to bf16
  cvt_bf16_4<<<2048, 256, 0, stream>>>((const float4*)x,     (ushort4*)xb,  MROWS*DIM/4);
  cvt_bf16_4<<<2048, 256, 0, stream>>>((const float4*)W_in,  (ushort4*)Wib, FC*DIM/4);
  cvt_bf16_4<<<1024, 256, 0, stream>>>((const float4*)W_out, (ushort4*)Wob, DIM*DIM/4);

  // 2) feat = x @ W_in^T + b_in   (8192 x 6144, K=2048), bf16 out
  gemm_bt<__hip_bfloat16><<<dim3(FC/128, MROWS/128), 256, 0, stream>>>(xb, Wib, b_in, feat, MROWS, FC, 2048);

  // 3) bidirectional chunked linear scan + gated output projection to o (fp32)
  scan_agg  <<<dim3(NCH/256, CHUNKS), 256, 0, stream>>>((const unsigned*)feat, aggP, (float4*)aggHF, (float4*)aggHR);
  scan_carry<<<64, 256, 0, stream>>>(aggP, aggHF, aggHR, cF, cR);
  scan_fwd  <<<dim3(NCH/256, CHUNKS), 256, 0, stream>>>((const unsigned*)feat, (const float4*)cF, (float2*)o);
  scan_rev  <<<dim3(NCH/256, CHUNKS), 256, 0, stream>>>((const unsigned*)feat, (const float4*)cR, (float2*)o);

  // 4) LayerNorm -> bf16 (oln aliases feat, which is now dead)
  layernorm_k<<<MROWS, 256, 0, stream>>>(o, gamma, beta, oln);

  // 5) out = o_ln @ W_out^T + b_out  (8192 x 2048, K=2048), fp32 out
  gemm_bt<float><<<dim3(DIM/128, MROWS/128), 256, 0, stream>>>(oln, Wob, b_out, out, MROWS, DIM, 2048);
}

// Round 3
// 440.419 us; speedup vs baseline: 1.3567x; 1.3567x over previous
//
#include <hip/hip_runtime.h>
#include <hip/hip_bf16.h>

// Problem constants
#define NSEQ 2048
#define NB   4
#define DIM  2048
#define HN   1024          // heads = DIM/2
#define FC   6144          // 3*DIM feat cols
#define MROWS 8192         // NSEQ*NB
#define CHUNKS 64
#define CLEN 32            // NSEQ/CHUNKS
#define NCH  4096          // NB*HN channels

typedef __bf16 bf16x8_t __attribute__((ext_vector_type(8)));
typedef float  f32x4_t  __attribute__((ext_vector_type(4)));

__device__ __forceinline__ float sigm(float x){ return 1.f/(1.f + __expf(-x)); }
__device__ __forceinline__ float bflo(unsigned p){ return __uint_as_float(p << 16); }
__device__ __forceinline__ float bfhi(unsigned p){ return __uint_as_float(p & 0xffff0000u); }
__device__ __forceinline__ unsigned short f2bf(float f){
  union { __hip_bfloat16 h; unsigned short u; } cv;
  cv.h = __float2bfloat16(f);
  return cv.u;
}

// ---------------------------------------------------------------- convert f32 -> bf16
__global__ __launch_bounds__(256) void cvt_bf16_4(const float4* __restrict__ in,
                                                  ushort4* __restrict__ out, int n4){
  int i = blockIdx.x * blockDim.x + threadIdx.x;
  int st = gridDim.x * blockDim.x;
  for (; i < n4; i += st){
    float4 v = in[i];
    ushort4 r;
    r.x = f2bf(v.x); r.y = f2bf(v.y); r.z = f2bf(v.z); r.w = f2bf(v.w);
    out[i] = r;
  }
}

// ---------------------------------------------------------------- bf16 NT GEMM + bias
// C[m,n] = sum_k A[m,k]*B[n,k] + bias[n].  A: MxK bf16 row-major, B: NxK bf16 row-major.
// 256x256 tile, BK=64, 8 waves (2Mx4N), per-wave 128x64 via 8x4 frags of 16x16x32 MFMA.
// Double-buffered LDS (128 KiB), issue-early staging, XOR-swizzled LDS granules,
// one barrier+drain per K-tile (drain hidden by ~2500cy of MFMA), setprio, XCD swizzle.
__device__ __forceinline__ void gl_lds16(const void* g, void* l){
  __builtin_amdgcn_global_load_lds((const __attribute__((address_space(1))) void*)g,
                                   (__attribute__((address_space(3))) void*)l, 16, 0, 0);
}

template <typename OutT>
__global__ __launch_bounds__(512, 2) void gemm256(const __hip_bfloat16* __restrict__ A,
                                                  const __hip_bfloat16* __restrict__ B,
                                                  const float* __restrict__ bias,
                                                  OutT* __restrict__ C,
                                                  int M, int N, int K, int nbx){
  // [buf0: A(16384) B(16384)][buf1: A B]  elements; 128 KiB total
  __shared__ __align__(16) __hip_bfloat16 smem[4*16384];
  const int tid  = threadIdx.x;
  const int wave = tid >> 6, lane = tid & 63;

  // T1: bijective XCD swizzle (gridDim.x % 8 == 0 guaranteed by launch)
  const int cpx = gridDim.x >> 3;
  const int wg  = (blockIdx.x & 7) * cpx + (blockIdx.x >> 3);
  const int bx = wg % nbx, by = wg / nbx;
  const int m0 = by * 256, n0 = bx * 256;

  const int wr = wave >> 2, wc = wave & 3;   // wave -> (2M x 4N) sub-tile
  const int r  = lane & 15, q = lane >> 4;   // fragment row / k-group
  const int kx = q ^ (r & 7);                // swizzled k-granule for ksub0

  // staging: thread loads granule g = i*512+tid of A and of B (granule=16B, 8 elems)
  // LDS dest linear (granule g -> offset g*8); global source pre-swizzled:
  //   row = g>>3, phys granule col = g&7 holds logical k16 = (g&7) ^ (row&7)
  int goffA[4], goffB[4], ldso[4];
  #pragma unroll
  for (int i = 0; i < 4; ++i){
    int g = i*512 + tid;
    int row = g >> 3;
    int k16 = (g & 7) ^ (row & 7);
    goffA[i] = (m0 + row) * K + k16*8;
    goffB[i] = (n0 + row) * K + k16*8;
    ldso[i]  = g * 8;
  }
  auto stage = [&](int kt, int bufo){
    #pragma unroll
    for (int i = 0; i < 4; ++i){
      gl_lds16(A + goffA[i] + kt, smem + bufo + ldso[i]);
      gl_lds16(B + goffB[i] + kt, smem + bufo + 16384 + ldso[i]);
    }
  };

  const int arow = wr*128 + r;   // + fm*16
  const int brow = wc*64  + r;   // + fn*16

  f32x4_t acc[8][4] = {};

  const int NT = K >> 6;
  stage(0, 0);
  __syncthreads();               // tile 0 landed (one cold-latency drain)
  int curo = 0;

  for (int t = 0; t < NT; ++t){
    if (t + 1 < NT) stage((t+1)*64, curo ^ 32768);   // issue-early into other buffer
    #pragma unroll
    for (int ksub = 0; ksub < 2; ++ksub){
      const int kphys = (kx ^ (ksub << 2)) << 3;     // swizzled element offset
      const __hip_bfloat16* Ab = smem + curo + arow*64 + kphys;
      const __hip_bfloat16* Bb = smem + curo + 16384 + brow*64 + kphys;
      bf16x8_t bfr[4];
      #pragma unroll
      for (int fn = 0; fn < 4; ++fn)
        bfr[fn] = *reinterpret_cast<const bf16x8_t*>(Bb + fn*1024);
      #pragma unroll
      for (int half = 0; half < 2; ++half){
        bf16x8_t af[4];
        #pragma unroll
        for (int i = 0; i < 4; ++i)
          af[i] = *reinterpret_cast<const bf16x8_t*>(Ab + (half*4 + i)*1024);
        __builtin_amdgcn_s_setprio(1);
        #pragma unroll
        for (int i = 0; i < 4; ++i)
          #pragma unroll
          for (int fn = 0; fn < 4; ++fn)
            acc[half*4 + i][fn] =
              __builtin_amdgcn_mfma_f32_16x16x32_bf16(af[i], bfr[fn], acc[half*4 + i][fn], 0, 0, 0);
        __builtin_amdgcn_s_setprio(0);
      }
    }
    __syncthreads();             // drains vmcnt: next tile landed; reads of curo done
    curo ^= 32768;
  }

  // epilogue: C/D layout col = lane&15, row = (lane>>4)*4 + j  (m89-verified)
  #pragma unroll
  for (int fn = 0; fn < 4; ++fn){
    int col = n0 + wc*64 + fn*16 + r;
    float bv = bias[col];
    #pragma unroll
    for (int fm = 0; fm < 8; ++fm){
      int row0 = m0 + wr*128 + fm*16 + q*4;
      #pragma unroll
      for (int j = 0; j < 4; ++j){
        float v = acc[fm][fn][j] + bv;
        if constexpr (__is_same(OutT, float))
          C[(size_t)(row0 + j)*N + col] = v;
        else
          C[(size_t)(row0 + j)*N + col] = __float2bfloat16(v);
      }
    }
  }
}

// ---------------------------------------------------------------- scan helpers
// feat viewed as uint pairs: row(n,b) = n*NB+b; uint offset = (n*NB+b)*3072 + h
//   + 0    -> inp pair (cols 2h, 2h+1)
//   + 1024 -> og  pair
//   + 2048 -> fg  pair
struct SV { float l0, l1, u00, u01, u10, u11; };
__device__ __forceinline__ SV stepv(const unsigned* __restrict__ fp, int rowu){
  unsigned pi = fp[rowu];
  unsigned pf = fp[rowu + 2048];
  SV s;
  s.l0 = sigm(bflo(pf)); s.l1 = sigm(bfhi(pf));
  float i0 = bflo(pi), i1 = bfhi(pi);
  i0 *= sigm(i0); i1 *= sigm(i1);            // silu
  float a0 = 1.f - s.l0, a1 = 1.f - s.l1;
  s.u00 = a0*i0; s.u01 = a0*i1; s.u10 = a1*i0; s.u11 = a1*i1;
  return s;
}

// S1: per-(channel, chunk) aggregates. P = prod lam (direction independent),
// hF = fwd local end-state, hR = rev local start-state. state layout [d][e].
__global__ __launch_bounds__(256) void scan_agg(const unsigned* __restrict__ feat,
    float* __restrict__ aggP, float4* __restrict__ aggHF, float4* __restrict__ aggHR){
  int ch = blockIdx.x*256 + threadIdx.x;   // 0..4095  (b*HN + h)
  int c  = blockIdx.y;
  int b = ch >> 10, h = ch & 1023;
  int base = b*3072 + h;
  int n0 = c*CLEN;
  float P0 = 1.f, P1 = 1.f;
  float f00=0,f01=0,f10=0,f11=0;
  for (int t = 0; t < CLEN; ++t){
    SV s = stepv(feat, (n0+t)*12288 + base);
    f00 = s.l0*f00 + s.u00; f01 = s.l0*f01 + s.u01;
    f10 = s.l1*f10 + s.u10; f11 = s.l1*f11 + s.u11;
    P0 *= s.l0; P1 *= s.l1;
  }
  float r00=0,r01=0,r10=0,r11=0;
  for (int t = CLEN-1; t >= 0; --t){
    SV s = stepv(feat, (n0+t)*12288 + base);
    r00 = s.l0*r00 + s.u00; r01 = s.l0*r01 + s.u01;
    r10 = s.l1*r10 + s.u10; r11 = s.l1*r11 + s.u11;
  }
  aggP[c*8192 + ch*2]     = P0;
  aggP[c*8192 + ch*2 + 1] = P1;
  aggHF[c*4096 + ch] = make_float4(f00,f01,f10,f11);
  aggHR[c*4096 + ch] = make_float4(r00,r01,r10,r11);
}

// S2: serial scan over chunk aggregates -> per-chunk carry-in states.
// thread per (ch,d,e): t = ch*4 + d*2 + e
__global__ __launch_bounds__(256) void scan_carry(const float* __restrict__ aggP,
    const float* __restrict__ aggHF, const float* __restrict__ aggHR,
    float* __restrict__ cF, float* __restrict__ cR){
  int t  = blockIdx.x*256 + threadIdx.x;   // 0..16383
  int pd = t >> 1;                         // ch*2 + d
  float s = 0.f;
  for (int c = 0; c < CHUNKS; ++c){
    cF[c*16384 + t] = s;
    s = aggP[c*8192 + pd]*s + aggHF[c*16384 + t];
  }
  s = 0.f;
  for (int c = CHUNKS-1; c >= 0; --c){
    cR[c*16384 + t] = s;
    s = aggP[c*8192 + pd]*s + aggHR[c*16384 + t];
  }
}

// S3a: forward pass, write o = sum_d og_d * fwd[d][e]   (fp32, (row, 2048))
__global__ __launch_bounds__(256) void scan_fwd(const unsigned* __restrict__ feat,
    const float4* __restrict__ cF, float2* __restrict__ o){
  int ch = blockIdx.x*256 + threadIdx.x;
  int c  = blockIdx.y;
  int b = ch >> 10, h = ch & 1023;
  int base = b*3072 + h;
  float4 hv = cF[c*4096 + ch];
  float h00=hv.x, h01=hv.y, h10=hv.z, h11=hv.w;
  for (int t = 0; t < CLEN; ++t){
    int n = c*CLEN + t;
    int rowu = n*12288 + base;
    SV s = stepv(feat, rowu);
    h00 = s.l0*h00 + s.u00; h01 = s.l0*h01 + s.u01;
    h10 = s.l1*h10 + s.u10; h11 = s.l1*h11 + s.u11;
    unsigned po = feat[rowu + 1024];
    float g0 = sigm(bflo(po)), g1 = sigm(bfhi(po));
    o[(n*NB + b)*1024 + h] = make_float2(g0*h00 + g1*h10, g0*h01 + g1*h11);
  }
}

// S3b: reverse pass, o += sum_d og_d * rev[d][e]
__global__ __launch_bounds__(256) void scan_rev(const unsigned* __restrict__ feat,
    const float4* __restrict__ cR, float2* __restrict__ o){
  int ch = blockIdx.x*256 + threadIdx.x;
  int c  = blockIdx.y;
  int b = ch >> 10, h = ch & 1023;
  int base = b*3072 + h;
  float4 hv = cR[c*4096 + ch];
  float h00=hv.x, h01=hv.y, h10=hv.z, h11=hv.w;
  for (int t = CLEN-1; t >= 0; --t){
    int n = c*CLEN + t;
    int rowu = n*12288 + base;
    SV s = stepv(feat, rowu);
    h00 = s.l0*h00 + s.u00; h01 = s.l0*h01 + s.u01;
    h10 = s.l1*h10 + s.u10; h11 = s.l1*h11 + s.u11;
    unsigned po = feat[rowu + 1024];
    float g0 = sigm(bflo(po)), g1 = sigm(bfhi(po));
    int idx = (n*NB + b)*1024 + h;
    float2 pv = o[idx];
    o[idx] = make_float2(pv.x + g0*h00 + g1*h10, pv.y + g0*h01 + g1*h11);
  }
}

// ---------------------------------------------------------------- LayerNorm over D, bf16 out
__global__ __launch_bounds__(256) void layernorm_k(const float* __restrict__ o,
    const float* __restrict__ gamma, const float* __restrict__ beta,
    __hip_bfloat16* __restrict__ out){
  int row = blockIdx.x, t = threadIdx.x;
  const float4* x = (const float4*)(o + (size_t)row*DIM);
  float4 a = x[t], b = x[t + 256];
  float s  = (a.x + a.y) + (a.z + a.w) + (b.x + b.y) + (b.z + b.w);
  float ss = (a.x*a.x + a.y*a.y) + (a.z*a.z + a.w*a.w)
           + (b.x*b.x + b.y*b.y) + (b.z*b.z + b.w*b.w);
  #pragma unroll
  for (int off = 32; off > 0; off >>= 1){
    s  += __shfl_down(s, off);
    ss += __shfl_down(ss, off);
  }
  __shared__ float red[8];
  int wv = t >> 6, ln = t & 63;
  if (ln == 0){ red[wv] = s; red[4 + wv] = ss; }
  __syncthreads();
  float S  = (red[0] + red[1]) + (red[2] + red[3]);
  float SS = (red[4] + red[5]) + (red[6] + red[7]);
  float mu = S * (1.f/DIM);
  float rs = rsqrtf(SS * (1.f/DIM) - mu*mu + 1e-5f);
  const float4* gp = (const float4*)gamma;
  const float4* bp = (const float4*)beta;
  float4 g0 = gp[t], g1 = gp[t + 256], be0 = bp[t], be1 = bp[t + 256];
  ushort4* op = (ushort4*)(out + (size_t)row*DIM);
  ushort4 r0, r1;
  r0.x = f2bf((a.x - mu)*rs*g0.x + be0.x);
  r0.y = f2bf((a.y - mu)*rs*g0.y + be0.y);
  r0.z = f2bf((a.z - mu)*rs*g0.z + be0.z);
  r0.w = f2bf((a.w - mu)*rs*g0.w + be0.w);
  r1.x = f2bf((b.x - mu)*rs*g1.x + be1.x);
  r1.y = f2bf((b.y - mu)*rs*g1.y + be1.y);
  r1.z = f2bf((b.z - mu)*rs*g1.z + be1.z);
  r1.w = f2bf((b.w - mu)*rs*g1.w + be1.w);
  op[t] = r0; op[t + 256] = r1;
}

// ---------------------------------------------------------------- launch
extern "C" void kernel_launch(void* const* d_in, const int* in_sizes, int n_in,
                              void* d_out, int out_size, void* d_ws, size_t ws_size,
                              hipStream_t stream){
  (void)in_sizes; (void)n_in; (void)out_size;
  const float* x     = (const float*)d_in[0];   // (N,B,D)
  const float* W_in  = (const float*)d_in[1];   // (3D,D)
  const float* b_in  = (const float*)d_in[2];   // (3D)
  const float* gamma = (const float*)d_in[3];   // (D)
  const float* beta  = (const float*)d_in[4];   // (D)
  const float* W_out = (const float*)d_in[5];   // (D,D)
  const float* b_out = (const float*)d_in[6];   // (D)
  float* out = (float*)d_out;                   // (N,B,D) fp32 (reference output dtype)

  // ---- workspace layout with aliasing (total 186 MiB) ----
  // [feat 96MiB][U 64MiB][Wob 8MiB][agg 18MiB]
  //   U: phase1 = xb(32MiB)+Wib(24MiB)  (dead after GEMM1)
  //      phase2 = o fp32 (64MiB)
  //   oln(32MiB) aliases feat (dead after scan_rev)
  char* p = (char*)d_ws;
  auto carve = [&](size_t bytes) -> char* {
    char* r = p; p += (bytes + 255) & ~(size_t)255; return r;
  };
  __hip_bfloat16* feat = (__hip_bfloat16*)carve((size_t)MROWS*FC*2);      // 96 MiB
  char* U              = carve((size_t)MROWS*DIM*4);                      // 64 MiB
  __hip_bfloat16* Wob  = (__hip_bfloat16*)carve((size_t)DIM*DIM*2);       //  8 MiB
  float* aggP  = (float*)carve((size_t)CHUNKS*8192*4);                    //  2 MiB
  float* aggHF = (float*)carve((size_t)CHUNKS*16384*4);                   //  4 MiB
  float* aggHR = (float*)carve((size_t)CHUNKS*16384*4);                   //  4 MiB
  float* cF    = (float*)carve((size_t)CHUNKS*16384*4);                   //  4 MiB
  float* cR    = (float*)carve((size_t)CHUNKS*16384*4);                   //  4 MiB
  if ((size_t)(p - (char*)d_ws) > ws_size) return;  // insufficient scratch

  __hip_bfloat16* xb  = (__hip_bfloat16*)U;                               // 32 MiB (phase 1)
  __hip_bfloat16* Wib = (__hip_bfloat16*)(U + (size_t)MROWS*DIM*2);       // 24 MiB (phase 1)
  float* o            = (float*)U;                                        // 64 MiB (phase 2+)
  __hip_bfloat16* oln = (__hip_bfloat16*)feat;                            // 32 MiB (phase 3)

  // 1) convert inputs to bf16
  cvt_bf16_4<<<2048, 256, 0, stream>>>((const float4*)x,     (ushort4*)xb,  MROWS*DIM/4);
  cvt_bf16_4<<<2048, 256, 0, stream>>>((const float4*)W_in,  (ushort4*)Wib, FC*DIM/4);
  cvt_bf16_4<<<1024, 256, 0, stream>>>((const float4*)W_out, (ushort4*)Wob, DIM*DIM/4);

  // 2) feat = x @ W_in^T + b_in   (8192 x 6144, K=2048), bf16 out; grid 768 (%8==0)
  gemm256<__hip_bfloat16><<<768, 512, 0, stream>>>(xb, Wib, b_in, feat, MROWS, FC, 2048, FC/256);

  // 3) bidirectional chunked linear scan + gated output projection to o (fp32)
  scan_agg  <<<dim3(NCH/256, CHUNKS), 256, 0, stream>>>((const unsigned*)feat, aggP, (float4*)aggHF, (float4*)aggHR);
  scan_carry<<<64, 256, 0, stream>>>(aggP, aggHF, aggHR, cF, cR);
  scan_fwd  <<<dim3(NCH/256, CHUNKS), 256, 0, stream>>>((const unsigned*)feat, (const float4*)cF, (float2*)o);
  scan_rev  <<<dim3(NCH/256, CHUNKS), 256, 0, stream>>>((const unsigned*)feat, (const float4*)cR, (float2*)o);

  // 4) LayerNorm -> bf16 (oln aliases feat, which is now dead)
  layernorm_k<<<MROWS, 256, 0, stream>>>(o, gamma, beta, oln);

  // 5) out = o_ln @ W_out^T + b_out  (8192 x 2048, K=2048), fp32 out; grid 256 (%8==0)
  gemm256<float><<<256, 512, 0, stream>>>(oln, Wob, b_out, out, MROWS, DIM, 2048, DIM/256);
}